// Round 12
// baseline (200.290 us; speedup 1.0000x reference)
//
#include <hip/hip_runtime.h>
#include <hip/hip_bf16.h>
#include <math.h>

typedef unsigned short u16;
typedef short bf16x8 __attribute__((ext_vector_type(8)));
typedef float f32x4 __attribute__((ext_vector_type(4)));

#define NB 8
#define NN 56          // h == w
#define M2 112         // 2n
#define EMB 192
#define D1 576
#define TOK (NB*NN*NN) // 25088

__device__ __forceinline__ float bf2f(unsigned int u) {
    union { unsigned int i; float f; } v; v.i = u << 16; return v.f;
}
__device__ __forceinline__ u16 f2bf(float f) {
    union { float f; unsigned int i; } v; v.f = f;
    unsigned int x = v.i;
    return (u16)((x + 0x7fffu + ((x >> 16) & 1u)) >> 16);
}
__device__ __forceinline__ float fast_silu(float x) {
    float e = __builtin_amdgcn_exp2f(-1.442695041f * x);
    return x * __builtin_amdgcn_rcpf(1.0f + e);
}
__device__ __forceinline__ void async16(void* lds, const void* g) {
    __builtin_amdgcn_global_load_lds(
        (const __attribute__((address_space(1))) void*)g,
        (__attribute__((address_space(3))) void*)lds, 16, 0, 0);
}

// ---------------- K0: fp32 -> bf16 convert (x, pw, qw, vw, ow) ------------
#define XCH (TOK*EMB/4)
#define WCH (D1*EMB/4)
__global__ __launch_bounds__(256) void convert_kernel(
    const float* __restrict__ x,
    const float* __restrict__ pw, const float* __restrict__ qw,
    const float* __restrict__ vw, const float* __restrict__ ow,
    u16* __restrict__ xb, u16* __restrict__ wb, u16* __restrict__ owb)
{
    int tid = blockIdx.x * 256 + threadIdx.x;
    const float* src; u16* dst; int off;
    if (tid < XCH) { src = x; dst = xb; off = tid; }
    else {
        int r = tid - XCH;
        int seg = r / WCH; off = r % WCH;
        if (seg == 0)      { src = pw; dst = wb; }
        else if (seg == 1) { src = qw; dst = wb + D1*EMB; }
        else if (seg == 2) { src = vw; dst = wb + 2*D1*EMB; }
        else if (seg == 3) { src = ow; dst = owb; }
        else return;
    }
    float4 f = *(const float4*)(src + off * 4);
    ushort4 o;
    o.x = f2bf(f.x); o.y = f2bf(f.y); o.z = f2bf(f.z); o.w = f2bf(f.w);
    *(ushort4*)(dst + off * 4) = o;
}

// ---------------- K1: RPE MLP + decay -> A1, A2 (fp32, 112 x 576 each) ----
__global__ __launch_bounds__(576) void rpe_kernel(
    const float* __restrict__ slope,
    const float* w0a, const float* b0a, const float* wsa, const float* bsa,
    const float* woa, const float* boa,
    const float* w0b, const float* b0b, const float* wsb, const float* bsb,
    const float* wob, const float* bob,
    float* __restrict__ A1, float* __restrict__ A2)
{
    int wq  = blockIdx.x / M2;
    int row = blockIdx.x % M2;
    const float* w0 = wq ? w0b : w0a;  const float* b0 = wq ? b0b : b0a;
    const float* ws = wq ? wsb : wsa;  const float* bs = wq ? bsb : bsa;
    const float* wo = wq ? wob : woa;  const float* bo = wq ? bob : boa;
    float* A = wq ? A2 : A1;

    float tval = (row == 0 || row == 56) ? 0.0f
               : (row < 56 ? (float)row : -(float)(row - 56));
    int kexp = (row == 0 || row == 56) ? 0 : (row < 56 ? row : 112 - row);

    __shared__ float h[32], g[32];
    int t = threadIdx.x;
    if (t < 32) h[t] = tval * w0[t] + b0[t];
    __syncthreads();
    for (int L = 0; L < 3; L++) {
        if (t < 32) g[t] = fmaxf(h[t], 0.0f);
        __syncthreads();
        float hn = 0.0f;
        if (t < 32) {
            hn = bs[L * 32 + t];
            for (int k = 0; k < 32; k++)
                hn = fmaf(g[k], ws[(L * 32 + t) * 32 + k], hn);
        }
        __syncthreads();
        if (t < 32) h[t] = hn;
        __syncthreads();
    }
    if (t < 32) g[t] = fmaxf(h[t], 0.0f);
    __syncthreads();

    float o = bo[t];
    for (int k = 0; k < 32; k++)
        o = fmaf(g[k], wo[t * 32 + k], o);

    float sl = slope[t];
    sl = 0.95f + 0.05f * fminf(fmaxf(sl, 0.0f), 1.0f);
    float dec = powf(sl, (float)kexp);
    A[row * D1 + t] = o * dec;
}

// ---------------- K1b: build Toeplitz matrices T[d][64][64] bf16 ----------
__global__ __launch_bounds__(256) void tbuild_kernel(
    const float* __restrict__ A1, const float* __restrict__ A2,
    u16* __restrict__ T1t, u16* __restrict__ T2t)
{
    int d = blockIdx.x;
    const float* src = blockIdx.y ? A2 : A1;
    u16* dst = blockIdx.y ? T2t : T1t;
    __shared__ float win[111];
    int t = threadIdx.x;
    if (t < 111) {
        int lag = t - 55;
        int rowi = lag + (lag < 0 ? 112 : 0);
        win[t] = src[rowi * D1 + d];
    }
    __syncthreads();
    int i = t >> 2, jq = (t & 3) * 16;
    u16 vals[16];
    #pragma unroll
    for (int jj = 0; jj < 16; jj++) {
        int j = jq + jj;
        float v = (i < 56 && j < 56) ? win[i - j + 55] : 0.0f;
        vals[jj] = f2bf(v);
    }
    u16* out = dst + ((size_t)d * 64 + i) * 64 + jq;
    *(uint4*)(out)     = *(uint4*)&vals[0];
    *(uint4*)(out + 8) = *(uint4*)&vals[8];
}

// ---------------- K2: MFMA proj, BK=32 6-step counted-vmcnt dbuf ----------
__global__ __launch_bounds__(512, 4) void proj_kernel(
    const u16* __restrict__ xb, const u16* __restrict__ wb,
    const float* __restrict__ pb, const float* __restrict__ qb,
    const float* __restrict__ vb,
    u16* __restrict__ P_T, u16* __restrict__ QV_T)
{
    __shared__ u16 lds[24576];          // 2 x {As 4096 u16, Bs 8192 u16}
    int m0 = blockIdx.x * 128, n0 = blockIdx.y * 64;
    int t = threadIdx.x;
    int l = t & 63, wave = t >> 6;          // 8 waves
    int wm = wave >> 2, wn = wave & 3;      // 2 m-halves x 4 n-quarters
    int col16 = l & 15, q = l >> 4;

    f32x4 accp[4], accq[4], accv[4];
    #pragma unroll
    for (int i = 0; i < 4; i++) {
        accp[i] = (f32x4){0,0,0,0};
        accq[i] = (f32x4){0,0,0,0};
        accv[i] = (f32x4){0,0,0,0};
    }

    auto stage = [&](int kc, int buf) {
        int bo = buf * 12288;
        {
            int slot = t;
            int r = slot >> 2, s = slot & 3;
            int g = s ^ (r & 3);
            async16(&lds[bo + slot * 8], xb + (m0 + r) * EMB + kc * 32 + g * 8);
        }
        #pragma unroll
        for (int ii = 0; ii < 2; ii++) {
            int slot = ii * 512 + t;
            int mat = slot >> 8, cc = slot & 255;
            int matsrc = mat < 3 ? mat : 2;
            int r = cc >> 2, s = cc & 3;
            int g = s ^ (r & 3);
            async16(&lds[bo + 4096 + slot * 8],
                    wb + matsrc * (D1 * EMB) + (n0 + r) * EMB + kc * 32 + g * 8);
        }
    };

    auto compute = [&](int buf) {
        int bo = buf * 12288;
        int cs = (q ^ (col16 & 3)) * 8;
        bf16x8 af[4];
        #pragma unroll
        for (int mt = 0; mt < 4; mt++)
            af[mt] = *(const bf16x8*)&lds[bo + (wm * 64 + mt * 16 + col16) * 32 + cs];
        bf16x8 bfr[3];
        #pragma unroll
        for (int mat = 0; mat < 3; mat++)
            bfr[mat] = *(const bf16x8*)&lds[bo + 4096 + mat * 2048 + (wn * 16 + col16) * 32 + cs];
        #pragma unroll
        for (int mt = 0; mt < 4; mt++) {
            accp[mt] = __builtin_amdgcn_mfma_f32_16x16x32_bf16(af[mt], bfr[0], accp[mt], 0, 0, 0);
            accq[mt] = __builtin_amdgcn_mfma_f32_16x16x32_bf16(af[mt], bfr[1], accq[mt], 0, 0, 0);
            accv[mt] = __builtin_amdgcn_mfma_f32_16x16x32_bf16(af[mt], bfr[2], accv[mt], 0, 0, 0);
        }
    };

    stage(0, 0);
    stage(1, 1);
    #pragma unroll
    for (int kc = 0; kc < 6; kc++) {
        int buf = kc & 1;
        if (kc < 5) {
            asm volatile("s_waitcnt vmcnt(3)" ::: "memory");
        } else {
            asm volatile("s_waitcnt vmcnt(0)" ::: "memory");
        }
        __builtin_amdgcn_s_barrier();
        compute(buf);
        if (kc < 4) {
            __builtin_amdgcn_s_barrier();
            stage(kc + 2, buf);
        }
    }

    int n = n0 + wn * 16 + col16;
    float pbv = pb[n], qbv = qb[n], vbv = vb[n];
    size_t drow = (size_t)n * TOK + m0 + wm * 64;
    #pragma unroll
    for (int mt = 0; mt < 4; mt++) {
        ushort4 o;
        o.x = f2bf(fast_silu(accp[mt][0] + pbv));
        o.y = f2bf(fast_silu(accp[mt][1] + pbv));
        o.z = f2bf(fast_silu(accp[mt][2] + pbv));
        o.w = f2bf(fast_silu(accp[mt][3] + pbv));
        *(ushort4*)&P_T[drow + mt * 16 + q * 4] = o;
    }
    #pragma unroll
    for (int mt = 0; mt < 4; mt++) {
        ushort4 o;
        o.x = f2bf(fast_silu(accq[mt][0] + qbv) * fast_silu(accv[mt][0] + vbv));
        o.y = f2bf(fast_silu(accq[mt][1] + qbv) * fast_silu(accv[mt][1] + vbv));
        o.z = f2bf(fast_silu(accq[mt][2] + qbv) * fast_silu(accv[mt][2] + vbv));
        o.w = f2bf(fast_silu(accq[mt][3] + qbv) * fast_silu(accv[mt][3] + vbv));
        *(ushort4*)&QV_T[drow + mt * 16 + q * 4] = o;
    }
}

// ---------------- K3: TNO, one block per d, b-loop with reg prefetch ------
// T1/T2 staged ONCE (was 8x). QV[b+1] and P[b] prefetched into registers;
// raw s_barrier + lgkmcnt-only waits keep them in flight (a __syncthreads
// vmcnt(0) would drain them). 576 blocks x ~50KB LDS -> all co-resident.
__global__ __launch_bounds__(256) void tno_mfma(
    const u16* __restrict__ QV_T, const u16* __restrict__ T1t,
    const u16* __restrict__ T2t, const u16* __restrict__ P_T,
    u16* __restrict__ U_T)
{
    __shared__ u16 T1s[4096];
    __shared__ u16 T2s[4096];
    __shared__ u16 Qn[64 * 72];
    __shared__ u16 Qt[64 * 72];
    __shared__ float O1f[56 * 68];
    int d = blockIdx.x;
    int t = threadIdx.x;
    size_t dbase = (size_t)d * TOK;

    #pragma unroll
    for (int k = 0; k < 2; k++) {
        int slot = t + k * 256;
        int i = slot >> 3, s = slot & 7;
        int g = s ^ (i & 7);
        async16(&T1s[slot * 8], T1t + ((size_t)d * 64 + i) * 64 + g * 8);
        async16(&T2s[slot * 8], T2t + ((size_t)d * 64 + i) * 64 + g * 8);
    }
    if (t < 56) {                       // K-pad cols: zero once, never rewritten
        uint4 z = {0, 0, 0, 0};
        *(uint4*)&Qn[t * 72 + 56] = z;
        *(uint4*)&Qt[t * 72 + 56] = z;
    }

    bool hasB = t < 136;                // chunk t+256 < 392
    int c0 = t, c1 = t + 256;
    int h0 = c0 / 7, w80 = (c0 % 7) * 8;
    int h1 = c1 / 7, w81 = (c1 % 7) * 8;

    uint4 qvA = *(const uint4*)(QV_T + dbase + c0 * 8);
    uint4 qvB = hasB ? *(const uint4*)(QV_T + dbase + c1 * 8) : (uint4){0,0,0,0};

    int l = t & 63, wave = t >> 6;
    int col16 = l & 15, q = l >> 4;

    for (int b = 0; b < 8; b++) {
        size_t base = dbase + (size_t)b * 3136;
        // publish QV[b] into Qn/Qt (reg -> LDS)
        {
            *(uint4*)&Qn[h0 * 72 + w80] = qvA;
            u16 e[8]; *(uint4*)e = qvA;
            #pragma unroll
            for (int k = 0; k < 8; k++) Qt[(w80 + k) * 72 + h0] = e[k];
        }
        if (hasB) {
            *(uint4*)&Qn[h1 * 72 + w81] = qvB;
            u16 e2[8]; *(uint4*)e2 = qvB;
            #pragma unroll
            for (int k = 0; k < 8; k++) Qt[(w81 + k) * 72 + h1] = e2[k];
        }
        // prefetch P[b] (used only at sweep -> long latency window)
        uint4 pv0 = *(const uint4*)(P_T + base + c0 * 8);
        uint4 pv1 = hasB ? *(const uint4*)(P_T + base + c1 * 8) : (uint4){0,0,0,0};

        if (b == 0) {
            __syncthreads();            // drains T-table async16 too (once)
        } else {
            asm volatile("s_waitcnt lgkmcnt(0)" ::: "memory");
            __builtin_amdgcn_s_barrier();
        }

        // prefetch QV[b+1]; hides under MFMA + O1f passes
        uint4 nqvA = {0,0,0,0}, nqvB = {0,0,0,0};
        if (b < 7) {
            size_t nbase = dbase + (size_t)(b + 1) * 3136;
            nqvA = *(const uint4*)(QV_T + nbase + c0 * 8);
            if (hasB) nqvB = *(const uint4*)(QV_T + nbase + c1 * 8);
        }

        f32x4 acc1[4], acc2[4];
        #pragma unroll
        for (int i = 0; i < 4; i++) { acc1[i] = (f32x4){0,0,0,0}; acc2[i] = (f32x4){0,0,0,0}; }

        #pragma unroll
        for (int kk = 0; kk < 2; kk++) {
            int sw = ((q + 4 * kk) ^ (col16 & 7)) * 8;
            bf16x8 bq1 = *(const bf16x8*)&Qn[(wave * 16 + col16) * 72 + kk * 32 + q * 8];
            bf16x8 bq2 = *(const bf16x8*)&Qt[(wave * 16 + col16) * 72 + kk * 32 + q * 8];
            #pragma unroll
            for (int mt = 0; mt < 4; mt++) {
                bf16x8 a1 = *(const bf16x8*)&T1s[(mt * 16 + col16) * 64 + sw];
                bf16x8 a2 = *(const bf16x8*)&T2s[(mt * 16 + col16) * 64 + sw];
                acc1[mt] = __builtin_amdgcn_mfma_f32_16x16x32_bf16(a1, bq1, acc1[mt], 0, 0, 0);
                acc2[mt] = __builtin_amdgcn_mfma_f32_16x16x32_bf16(a2, bq2, acc2[mt], 0, 0, 0);
            }
        }

        {   // pass1 C: m = w-out, n = h  -> O1f[h][w]
            int n = wave * 16 + col16;
            if (n < 56) {
                #pragma unroll
                for (int mt = 0; mt < 4; mt++)
                    #pragma unroll
                    for (int r = 0; r < 4; r++) {
                        int m = mt * 16 + q * 4 + r;
                        if (m < 56) O1f[n * 68 + m] = acc1[mt][r];
                    }
            }
        }
        asm volatile("s_waitcnt lgkmcnt(0)" ::: "memory");
        __builtin_amdgcn_s_barrier();
        {   // pass2 C: m = h-out, n = w  -> O1f[h][w] += o2
            int n = wave * 16 + col16;
            if (n < 56) {
                #pragma unroll
                for (int mt = 0; mt < 4; mt++)
                    #pragma unroll
                    for (int r = 0; r < 4; r++) {
                        int m = mt * 16 + q * 4 + r;
                        if (m < 56) O1f[m * 68 + n] += acc2[mt][r];
                    }
            }
        }
        asm volatile("s_waitcnt lgkmcnt(0)" ::: "memory");
        __builtin_amdgcn_s_barrier();
        {   // sweep chunk c0
            f32x4 s0 = *(const f32x4*)&O1f[h0 * 68 + w80];
            f32x4 s1 = *(const f32x4*)&O1f[h0 * 68 + w80 + 4];
            u16 pe[8]; *(uint4*)pe = pv0;
            u16 ue[8];
            #pragma unroll
            for (int k = 0; k < 4; k++) ue[k] = f2bf(bf2f(pe[k]) * s0[k]);
            #pragma unroll
            for (int k = 0; k < 4; k++) ue[4 + k] = f2bf(bf2f(pe[4 + k]) * s1[k]);
            *(uint4*)(U_T + base + c0 * 8) = *(uint4*)ue;
        }
        if (hasB) {  // sweep chunk c1
            f32x4 s0 = *(const f32x4*)&O1f[h1 * 68 + w81];
            f32x4 s1 = *(const f32x4*)&O1f[h1 * 68 + w81 + 4];
            u16 pe[8]; *(uint4*)pe = pv1;
            u16 ue[8];
            #pragma unroll
            for (int k = 0; k < 4; k++) ue[k] = f2bf(bf2f(pe[k]) * s0[k]);
            #pragma unroll
            for (int k = 0; k < 4; k++) ue[4 + k] = f2bf(bf2f(pe[4 + k]) * s1[k]);
            *(uint4*)(U_T + base + c1 * 8) = *(uint4*)ue;
        }
        __builtin_amdgcn_s_barrier();   // O1f/Qn/Qt WAR vs next iteration
        qvA = nqvA; qvB = nqvB;
    }
}

// ---------------- K5: outproj, full-EMB per block, single pass over U_T ---
__global__ __launch_bounds__(512, 2) void outproj_kernel(
    const u16* __restrict__ U_T, const u16* __restrict__ owb,
    const float* __restrict__ ob, float* __restrict__ out)
{
    __shared__ char ldsraw[98304];          // 96 KB
    u16* Uscr = (u16*)ldsraw;               // 2 x 8192 u16  [dd 64][tok 128]
    u16* As   = (u16*)(ldsraw + 32768);     // 8192 u16      [tok 128][d 64] swz
    u16* Bs   = (u16*)(ldsraw + 49152);     // 2 x 12288 u16 [e 192][d 64] swz
    int m0 = blockIdx.x * 128;
    int t = threadIdx.x;
    int l = t & 63, wave = t >> 6;          // 8 waves
    int wm = wave >> 2, wn = wave & 3;      // 2 m-halves x 4 n-quarters(48)
    int col16 = l & 15, q = l >> 4;

    f32x4 acc[4][3];
    #pragma unroll
    for (int i = 0; i < 4; i++)
        #pragma unroll
        for (int j = 0; j < 3; j++) acc[i][j] = (f32x4){0,0,0,0};

    auto stage = [&](int k0, int buf) {     // 5 async16 per thread
        u16* Us  = Uscr + buf * 8192;
        u16* Bss = Bs   + buf * 12288;
        #pragma unroll
        for (int ii = 0; ii < 2; ii++) {
            int slot = ii * 512 + t;
            int dd = slot >> 4, tk = slot & 15;
            async16(&Us[slot * 8],
                    U_T + (size_t)(k0 * 64 + dd) * TOK + m0 + tk * 8);
        }
        #pragma unroll
        for (int ii = 0; ii < 3; ii++) {
            int slot = ii * 512 + t;
            int r = slot >> 3, s = slot & 7;
            int g = s ^ (r & 7);
            async16(&Bss[slot * 8], owb + r * D1 + k0 * 64 + g * 8);
        }
    };

    stage(0, 0);
    for (int k0 = 0; k0 < 9; k0++) {
        int buf = k0 & 1;
        if (k0 < 8) {
            stage(k0 + 1, buf ^ 1);
            asm volatile("s_waitcnt vmcnt(5)" ::: "memory");
        } else {
            asm volatile("s_waitcnt vmcnt(0)" ::: "memory");
        }
        __builtin_amdgcn_s_barrier();
        u16* Us = Uscr + buf * 8192;
        #pragma unroll
        for (int ii = 0; ii < 2; ii++) {
            int c = ii * 512 + t;
            int tok = c & 127, dc = c >> 7;
            u16 e[8];
            #pragma unroll
            for (int j = 0; j < 8; j++)
                e[j] = Us[(dc * 8 + j) * 128 + tok];
            int s = dc ^ (tok & 7);
            *(uint4*)&As[tok * 64 + s * 8] = *(uint4*)e;
        }
        asm volatile("s_waitcnt lgkmcnt(0)" ::: "memory");
        __builtin_amdgcn_s_barrier();

        u16* Bss = Bs + buf * 12288;
        #pragma unroll
        for (int kk = 0; kk < 2; kk++) {
            int sw = ((q + 4 * kk) ^ (col16 & 7)) * 8;
            bf16x8 af[4];
            #pragma unroll
            for (int mt = 0; mt < 4; mt++)
                af[mt] = *(const bf16x8*)&As[(wm * 64 + mt * 16 + col16) * 64 + sw];
            bf16x8 bfr[3];
            #pragma unroll
            for (int nt = 0; nt < 3; nt++)
                bfr[nt] = *(const bf16x8*)&Bss[(wn * 48 + nt * 16 + col16) * 64 + sw];
            #pragma unroll
            for (int mt = 0; mt < 4; mt++)
                #pragma unroll
                for (int nt = 0; nt < 3; nt++)
                    acc[mt][nt] = __builtin_amdgcn_mfma_f32_16x16x32_bf16(
                        af[mt], bfr[nt], acc[mt][nt], 0, 0, 0);
        }
        asm volatile("s_waitcnt lgkmcnt(0)" ::: "memory");
        __builtin_amdgcn_s_barrier();
    }

    #pragma unroll
    for (int nt = 0; nt < 3; nt++) {
        int n = wn * 48 + nt * 16 + col16;
        float obv = ob[n];
        #pragma unroll
        for (int mt = 0; mt < 4; mt++)
            #pragma unroll
            for (int r = 0; r < 4; r++)
                out[(size_t)(m0 + wm * 64 + mt * 16 + q * 4 + r) * EMB + n] =
                    acc[mt][nt][r] + obv;
    }
}

extern "C" void kernel_launch(void* const* d_in, const int* in_sizes, int n_in,
                              void* d_out, int out_size, void* d_ws, size_t ws_size,
                              hipStream_t stream)
{
    (void)in_sizes; (void)n_in; (void)out_size; (void)ws_size;
    const float* x     = (const float*)d_in[0];
    const float* p_w   = (const float*)d_in[1];
    const float* p_b   = (const float*)d_in[2];
    const float* q_w   = (const float*)d_in[3];
    const float* q_b   = (const float*)d_in[4];
    const float* v_w   = (const float*)d_in[5];
    const float* v_b   = (const float*)d_in[6];
    const float* o_w   = (const float*)d_in[7];
    const float* o_b   = (const float*)d_in[8];
    const float* slope = (const float*)d_in[9];
    const float* t1_w0 = (const float*)d_in[10];
    const float* t1_b0 = (const float*)d_in[11];
    const float* t1_ws = (const float*)d_in[12];
    const float* t1_bs = (const float*)d_in[13];
    const float* t1_wo = (const float*)d_in[14];
    const float* t1_bo = (const float*)d_in[15];
    const float* t2_w0 = (const float*)d_in[16];
    const float* t2_b0 = (const float*)d_in[17];
    const float* t2_ws = (const float*)d_in[18];
    const float* t2_bs = (const float*)d_in[19];
    const float* t2_wo = (const float*)d_in[20];
    const float* t2_bo = (const float*)d_in[21];

    char* ws = (char*)d_ws;
    float* A1  = (float*)ws;                     // 258048 B
    float* A2  = (float*)(ws + 258048);          // 258048 B
    u16*   PT  = (u16*)(ws + 516096);            // 28901376 B (P_T)
    u16*   QVT = (u16*)(ws + 29417472);          // 28901376 B
    u16*   UT  = (u16*)(ws + 58318848);          // 28901376 B
    u16*   xb  = (u16*)(ws + 87220224);          // 9633792 B
    u16*   wb  = (u16*)(ws + 96854016);          // 663552 B
    u16*   owb = (u16*)(ws + 97517568);          // 221184 B
    u16*   T1t = (u16*)(ws + 97738752);          // 4718592 B
    u16*   T2t = (u16*)(ws + 102457344);         // 4718592 B

    convert_kernel<<<(XCH + 4*WCH + 255) / 256, 256, 0, stream>>>(
        x, p_w, q_w, v_w, o_w, xb, wb, owb);
    rpe_kernel<<<224, 576, 0, stream>>>(slope,
        t1_w0, t1_b0, t1_ws, t1_bs, t1_wo, t1_bo,
        t2_w0, t2_b0, t2_ws, t2_bs, t2_wo, t2_bo, A1, A2);
    tbuild_kernel<<<dim3(576, 2), 256, 0, stream>>>(A1, A2, T1t, T2t);
    proj_kernel<<<dim3(TOK / 128, D1 / 64), 512, 0, stream>>>(
        xb, wb, p_b, q_b, v_b, PT, QVT);
    tno_mfma<<<D1, 256, 0, stream>>>(QVT, T1t, T2t, PT, UT);
    outproj_kernel<<<TOK / 128, 512, 0, stream>>>(
        UT, owb, o_b, (float*)d_out);
}

// Round 13
// 194.100 us; speedup vs baseline: 1.0319x; 1.0319x over previous
//
#include <hip/hip_runtime.h>
#include <hip/hip_bf16.h>
#include <math.h>

typedef unsigned short u16;
typedef short bf16x8 __attribute__((ext_vector_type(8)));
typedef float f32x4 __attribute__((ext_vector_type(4)));

#define NB 8
#define NN 56          // h == w
#define M2 112         // 2n
#define EMB 192
#define D1 576
#define TOK (NB*NN*NN) // 25088

__device__ __forceinline__ float bf2f(unsigned int u) {
    union { unsigned int i; float f; } v; v.i = u << 16; return v.f;
}
__device__ __forceinline__ u16 f2bf(float f) {
    union { float f; unsigned int i; } v; v.f = f;
    unsigned int x = v.i;
    return (u16)((x + 0x7fffu + ((x >> 16) & 1u)) >> 16);
}
__device__ __forceinline__ float fast_silu(float x) {
    float e = __builtin_amdgcn_exp2f(-1.442695041f * x);
    return x * __builtin_amdgcn_rcpf(1.0f + e);
}
__device__ __forceinline__ void async16(void* lds, const void* g) {
    __builtin_amdgcn_global_load_lds(
        (const __attribute__((address_space(1))) void*)g,
        (__attribute__((address_space(3))) void*)lds, 16, 0, 0);
}

// ---------------- K0: fp32 -> bf16 convert (x, pw, qw, vw, ow) ------------
#define XCH (TOK*EMB/4)
#define WCH (D1*EMB/4)
__global__ __launch_bounds__(256) void convert_kernel(
    const float* __restrict__ x,
    const float* __restrict__ pw, const float* __restrict__ qw,
    const float* __restrict__ vw, const float* __restrict__ ow,
    u16* __restrict__ xb, u16* __restrict__ wb, u16* __restrict__ owb)
{
    int tid = blockIdx.x * 256 + threadIdx.x;
    const float* src; u16* dst; int off;
    if (tid < XCH) { src = x; dst = xb; off = tid; }
    else {
        int r = tid - XCH;
        int seg = r / WCH; off = r % WCH;
        if (seg == 0)      { src = pw; dst = wb; }
        else if (seg == 1) { src = qw; dst = wb + D1*EMB; }
        else if (seg == 2) { src = vw; dst = wb + 2*D1*EMB; }
        else if (seg == 3) { src = ow; dst = owb; }
        else return;
    }
    float4 f = *(const float4*)(src + off * 4);
    ushort4 o;
    o.x = f2bf(f.x); o.y = f2bf(f.y); o.z = f2bf(f.z); o.w = f2bf(f.w);
    *(ushort4*)(dst + off * 4) = o;
}

// ---------------- K1: RPE MLP + decay -> A1, A2 (fp32, 112 x 576 each) ----
__global__ __launch_bounds__(576) void rpe_kernel(
    const float* __restrict__ slope,
    const float* w0a, const float* b0a, const float* wsa, const float* bsa,
    const float* woa, const float* boa,
    const float* w0b, const float* b0b, const float* wsb, const float* bsb,
    const float* wob, const float* bob,
    float* __restrict__ A1, float* __restrict__ A2)
{
    int wq  = blockIdx.x / M2;
    int row = blockIdx.x % M2;
    const float* w0 = wq ? w0b : w0a;  const float* b0 = wq ? b0b : b0a;
    const float* ws = wq ? wsb : wsa;  const float* bs = wq ? bsb : bsa;
    const float* wo = wq ? wob : woa;  const float* bo = wq ? bob : boa;
    float* A = wq ? A2 : A1;

    float tval = (row == 0 || row == 56) ? 0.0f
               : (row < 56 ? (float)row : -(float)(row - 56));
    int kexp = (row == 0 || row == 56) ? 0 : (row < 56 ? row : 112 - row);

    __shared__ float h[32], g[32];
    int t = threadIdx.x;
    if (t < 32) h[t] = tval * w0[t] + b0[t];
    __syncthreads();
    for (int L = 0; L < 3; L++) {
        if (t < 32) g[t] = fmaxf(h[t], 0.0f);
        __syncthreads();
        float hn = 0.0f;
        if (t < 32) {
            hn = bs[L * 32 + t];
            for (int k = 0; k < 32; k++)
                hn = fmaf(g[k], ws[(L * 32 + t) * 32 + k], hn);
        }
        __syncthreads();
        if (t < 32) h[t] = hn;
        __syncthreads();
    }
    if (t < 32) g[t] = fmaxf(h[t], 0.0f);
    __syncthreads();

    float o = bo[t];
    for (int k = 0; k < 32; k++)
        o = fmaf(g[k], wo[t * 32 + k], o);

    float sl = slope[t];
    sl = 0.95f + 0.05f * fminf(fmaxf(sl, 0.0f), 1.0f);
    float dec = powf(sl, (float)kexp);
    A[row * D1 + t] = o * dec;
}

// ---------------- K1b: build Toeplitz matrices T[d][64][64] bf16 ----------
__global__ __launch_bounds__(256) void tbuild_kernel(
    const float* __restrict__ A1, const float* __restrict__ A2,
    u16* __restrict__ T1t, u16* __restrict__ T2t)
{
    int d = blockIdx.x;
    const float* src = blockIdx.y ? A2 : A1;
    u16* dst = blockIdx.y ? T2t : T1t;
    __shared__ float win[111];
    int t = threadIdx.x;
    if (t < 111) {
        int lag = t - 55;
        int rowi = lag + (lag < 0 ? 112 : 0);
        win[t] = src[rowi * D1 + d];
    }
    __syncthreads();
    int i = t >> 2, jq = (t & 3) * 16;
    u16 vals[16];
    #pragma unroll
    for (int jj = 0; jj < 16; jj++) {
        int j = jq + jj;
        float v = (i < 56 && j < 56) ? win[i - j + 55] : 0.0f;
        vals[jj] = f2bf(v);
    }
    u16* out = dst + ((size_t)d * 64 + i) * 64 + jq;
    *(uint4*)(out)     = *(uint4*)&vals[0];
    *(uint4*)(out + 8) = *(uint4*)&vals[8];
}

// ---------------- K2: MFMA proj, BK=32 6-step counted-vmcnt dbuf ----------
// (R11 measured-best: 40.6-40.9 us.)
__global__ __launch_bounds__(512, 4) void proj_kernel(
    const u16* __restrict__ xb, const u16* __restrict__ wb,
    const float* __restrict__ pb, const float* __restrict__ qb,
    const float* __restrict__ vb,
    u16* __restrict__ P_T, u16* __restrict__ QV_T)
{
    __shared__ u16 lds[24576];          // 2 x {As 4096 u16, Bs 8192 u16}
    int m0 = blockIdx.x * 128, n0 = blockIdx.y * 64;
    int t = threadIdx.x;
    int l = t & 63, wave = t >> 6;          // 8 waves
    int wm = wave >> 2, wn = wave & 3;      // 2 m-halves x 4 n-quarters
    int col16 = l & 15, q = l >> 4;

    f32x4 accp[4], accq[4], accv[4];
    #pragma unroll
    for (int i = 0; i < 4; i++) {
        accp[i] = (f32x4){0,0,0,0};
        accq[i] = (f32x4){0,0,0,0};
        accv[i] = (f32x4){0,0,0,0};
    }

    auto stage = [&](int kc, int buf) {
        int bo = buf * 12288;
        {
            int slot = t;
            int r = slot >> 2, s = slot & 3;
            int g = s ^ (r & 3);
            async16(&lds[bo + slot * 8], xb + (m0 + r) * EMB + kc * 32 + g * 8);
        }
        #pragma unroll
        for (int ii = 0; ii < 2; ii++) {
            int slot = ii * 512 + t;
            int mat = slot >> 8, cc = slot & 255;
            int matsrc = mat < 3 ? mat : 2;
            int r = cc >> 2, s = cc & 3;
            int g = s ^ (r & 3);
            async16(&lds[bo + 4096 + slot * 8],
                    wb + matsrc * (D1 * EMB) + (n0 + r) * EMB + kc * 32 + g * 8);
        }
    };

    auto compute = [&](int buf) {
        int bo = buf * 12288;
        int cs = (q ^ (col16 & 3)) * 8;
        bf16x8 af[4];
        #pragma unroll
        for (int mt = 0; mt < 4; mt++)
            af[mt] = *(const bf16x8*)&lds[bo + (wm * 64 + mt * 16 + col16) * 32 + cs];
        bf16x8 bfr[3];
        #pragma unroll
        for (int mat = 0; mat < 3; mat++)
            bfr[mat] = *(const bf16x8*)&lds[bo + 4096 + mat * 2048 + (wn * 16 + col16) * 32 + cs];
        #pragma unroll
        for (int mt = 0; mt < 4; mt++) {
            accp[mt] = __builtin_amdgcn_mfma_f32_16x16x32_bf16(af[mt], bfr[0], accp[mt], 0, 0, 0);
            accq[mt] = __builtin_amdgcn_mfma_f32_16x16x32_bf16(af[mt], bfr[1], accq[mt], 0, 0, 0);
            accv[mt] = __builtin_amdgcn_mfma_f32_16x16x32_bf16(af[mt], bfr[2], accv[mt], 0, 0, 0);
        }
    };

    stage(0, 0);
    stage(1, 1);
    #pragma unroll
    for (int kc = 0; kc < 6; kc++) {
        int buf = kc & 1;
        if (kc < 5) {
            asm volatile("s_waitcnt vmcnt(3)" ::: "memory");
        } else {
            asm volatile("s_waitcnt vmcnt(0)" ::: "memory");
        }
        __builtin_amdgcn_s_barrier();
        compute(buf);
        if (kc < 4) {
            __builtin_amdgcn_s_barrier();
            stage(kc + 2, buf);
        }
    }

    int n = n0 + wn * 16 + col16;
    float pbv = pb[n], qbv = qb[n], vbv = vb[n];
    size_t drow = (size_t)n * TOK + m0 + wm * 64;
    #pragma unroll
    for (int mt = 0; mt < 4; mt++) {
        ushort4 o;
        o.x = f2bf(fast_silu(accp[mt][0] + pbv));
        o.y = f2bf(fast_silu(accp[mt][1] + pbv));
        o.z = f2bf(fast_silu(accp[mt][2] + pbv));
        o.w = f2bf(fast_silu(accp[mt][3] + pbv));
        *(ushort4*)&P_T[drow + mt * 16 + q * 4] = o;
    }
    #pragma unroll
    for (int mt = 0; mt < 4; mt++) {
        ushort4 o;
        o.x = f2bf(fast_silu(accq[mt][0] + qbv) * fast_silu(accv[mt][0] + vbv));
        o.y = f2bf(fast_silu(accq[mt][1] + qbv) * fast_silu(accv[mt][1] + vbv));
        o.z = f2bf(fast_silu(accq[mt][2] + qbv) * fast_silu(accv[mt][2] + vbv));
        o.w = f2bf(fast_silu(accq[mt][3] + qbv) * fast_silu(accv[mt][3] + vbv));
        *(ushort4*)&QV_T[drow + mt * 16 + q * 4] = o;
    }
}

// ---------------- K3: fused MFMA TNO (R10 form, component of best total) --
__global__ __launch_bounds__(256) void tno_mfma(
    const u16* __restrict__ QV_T, const u16* __restrict__ T1t,
    const u16* __restrict__ T2t, const u16* __restrict__ P_T,
    u16* __restrict__ U_T)
{
    __shared__ u16 T1s[4096];
    __shared__ u16 T2s[4096];
    __shared__ u16 Qn[64 * 72];
    __shared__ u16 Qt[64 * 72];
    __shared__ float O1f[56 * 68];
    int d = blockIdx.x, b = blockIdx.y;
    int t = threadIdx.x;
    size_t base = (size_t)d * TOK + (size_t)b * 3136;

    uint4 pv0 = *(const uint4*)(P_T + base + t * 8);
    uint4 pv1 = {0,0,0,0};
    bool has2 = (t + 256) < 392;
    if (has2) pv1 = *(const uint4*)(P_T + base + (t + 256) * 8);

    #pragma unroll
    for (int k = 0; k < 2; k++) {
        int slot = t + k * 256;
        int i = slot >> 3, s = slot & 7;
        int g = s ^ (i & 7);
        async16(&T1s[slot * 8], T1t + ((size_t)d * 64 + i) * 64 + g * 8);
        async16(&T2s[slot * 8], T2t + ((size_t)d * 64 + i) * 64 + g * 8);
    }
    for (int c = t; c < 392; c += 256) {
        int h = c / 7, w8 = (c % 7) * 8;
        uint4 v = *(const uint4*)(QV_T + base + c * 8);
        *(uint4*)&Qn[h * 72 + w8] = v;
        u16 e[8];
        *(uint4*)e = v;
        #pragma unroll
        for (int k = 0; k < 8; k++)
            Qt[(w8 + k) * 72 + h] = e[k];
    }
    if (t < 56) {
        uint4 z = {0, 0, 0, 0};
        *(uint4*)&Qn[t * 72 + 56] = z;
        *(uint4*)&Qt[t * 72 + 56] = z;
    }
    __syncthreads();

    int l = t & 63, wave = t >> 6;
    int col16 = l & 15, q = l >> 4;

    f32x4 acc1[4], acc2[4];
    #pragma unroll
    for (int i = 0; i < 4; i++) { acc1[i] = (f32x4){0,0,0,0}; acc2[i] = (f32x4){0,0,0,0}; }

    #pragma unroll
    for (int kk = 0; kk < 2; kk++) {
        int sw = ((q + 4 * kk) ^ (col16 & 7)) * 8;
        bf16x8 bq1 = *(const bf16x8*)&Qn[(wave * 16 + col16) * 72 + kk * 32 + q * 8];
        bf16x8 bq2 = *(const bf16x8*)&Qt[(wave * 16 + col16) * 72 + kk * 32 + q * 8];
        #pragma unroll
        for (int mt = 0; mt < 4; mt++) {
            bf16x8 a1 = *(const bf16x8*)&T1s[(mt * 16 + col16) * 64 + sw];
            bf16x8 a2 = *(const bf16x8*)&T2s[(mt * 16 + col16) * 64 + sw];
            acc1[mt] = __builtin_amdgcn_mfma_f32_16x16x32_bf16(a1, bq1, acc1[mt], 0, 0, 0);
            acc2[mt] = __builtin_amdgcn_mfma_f32_16x16x32_bf16(a2, bq2, acc2[mt], 0, 0, 0);
        }
    }

    {
        int n = wave * 16 + col16;
        if (n < 56) {
            #pragma unroll
            for (int mt = 0; mt < 4; mt++)
                #pragma unroll
                for (int r = 0; r < 4; r++) {
                    int m = mt * 16 + q * 4 + r;
                    if (m < 56) O1f[n * 68 + m] = acc1[mt][r];
                }
        }
    }
    __syncthreads();
    {
        int n = wave * 16 + col16;
        if (n < 56) {
            #pragma unroll
            for (int mt = 0; mt < 4; mt++)
                #pragma unroll
                for (int r = 0; r < 4; r++) {
                    int m = mt * 16 + q * 4 + r;
                    if (m < 56) O1f[m * 68 + n] += acc2[mt][r];
                }
        }
    }
    __syncthreads();
    {
        int c = t;
        int h = c / 7, w8 = (c % 7) * 8;
        f32x4 s0 = *(const f32x4*)&O1f[h * 68 + w8];
        f32x4 s1 = *(const f32x4*)&O1f[h * 68 + w8 + 4];
        u16 pe[8];
        *(uint4*)pe = pv0;
        u16 ue[8];
        #pragma unroll
        for (int k = 0; k < 4; k++) ue[k] = f2bf(bf2f(pe[k]) * s0[k]);
        #pragma unroll
        for (int k = 0; k < 4; k++) ue[4 + k] = f2bf(bf2f(pe[4 + k]) * s1[k]);
        *(uint4*)(U_T + base + c * 8) = *(uint4*)ue;
    }
    if (has2) {
        int c = t + 256;
        int h = c / 7, w8 = (c % 7) * 8;
        f32x4 s0 = *(const f32x4*)&O1f[h * 68 + w8];
        f32x4 s1 = *(const f32x4*)&O1f[h * 68 + w8 + 4];
        u16 pe[8];
        *(uint4*)pe = pv1;
        u16 ue[8];
        #pragma unroll
        for (int k = 0; k < 4; k++) ue[k] = f2bf(bf2f(pe[k]) * s0[k]);
        #pragma unroll
        for (int k = 0; k < 4; k++) ue[4 + k] = f2bf(bf2f(pe[4 + k]) * s1[k]);
        *(uint4*)(U_T + base + c * 8) = *(uint4*)ue;
    }
}

// ---------------- K5: outproj, full-EMB per block, single pass over U_T ---
__global__ __launch_bounds__(512, 2) void outproj_kernel(
    const u16* __restrict__ U_T, const u16* __restrict__ owb,
    const float* __restrict__ ob, float* __restrict__ out)
{
    __shared__ char ldsraw[98304];          // 96 KB
    u16* Uscr = (u16*)ldsraw;               // 2 x 8192 u16  [dd 64][tok 128]
    u16* As   = (u16*)(ldsraw + 32768);     // 8192 u16      [tok 128][d 64] swz
    u16* Bs   = (u16*)(ldsraw + 49152);     // 2 x 12288 u16 [e 192][d 64] swz
    int m0 = blockIdx.x * 128;
    int t = threadIdx.x;
    int l = t & 63, wave = t >> 6;          // 8 waves
    int wm = wave >> 2, wn = wave & 3;      // 2 m-halves x 4 n-quarters(48)
    int col16 = l & 15, q = l >> 4;

    f32x4 acc[4][3];
    #pragma unroll
    for (int i = 0; i < 4; i++)
        #pragma unroll
        for (int j = 0; j < 3; j++) acc[i][j] = (f32x4){0,0,0,0};

    auto stage = [&](int k0, int buf) {     // 5 async16 per thread
        u16* Us  = Uscr + buf * 8192;
        u16* Bss = Bs   + buf * 12288;
        #pragma unroll
        for (int ii = 0; ii < 2; ii++) {
            int slot = ii * 512 + t;
            int dd = slot >> 4, tk = slot & 15;
            async16(&Us[slot * 8],
                    U_T + (size_t)(k0 * 64 + dd) * TOK + m0 + tk * 8);
        }
        #pragma unroll
        for (int ii = 0; ii < 3; ii++) {
            int slot = ii * 512 + t;
            int r = slot >> 3, s = slot & 7;
            int g = s ^ (r & 7);
            async16(&Bss[slot * 8], owb + r * D1 + k0 * 64 + g * 8);
        }
    };

    stage(0, 0);
    for (int k0 = 0; k0 < 9; k0++) {
        int buf = k0 & 1;
        if (k0 < 8) {
            stage(k0 + 1, buf ^ 1);
            asm volatile("s_waitcnt vmcnt(5)" ::: "memory");
        } else {
            asm volatile("s_waitcnt vmcnt(0)" ::: "memory");
        }
        __builtin_amdgcn_s_barrier();
        u16* Us = Uscr + buf * 8192;
        #pragma unroll
        for (int ii = 0; ii < 2; ii++) {
            int c = ii * 512 + t;
            int tok = c & 127, dc = c >> 7;
            u16 e[8];
            #pragma unroll
            for (int j = 0; j < 8; j++)
                e[j] = Us[(dc * 8 + j) * 128 + tok];
            int s = dc ^ (tok & 7);
            *(uint4*)&As[tok * 64 + s * 8] = *(uint4*)e;
        }
        asm volatile("s_waitcnt lgkmcnt(0)" ::: "memory");
        __builtin_amdgcn_s_barrier();

        u16* Bss = Bs + buf * 12288;
        #pragma unroll
        for (int kk = 0; kk < 2; kk++) {
            int sw = ((q + 4 * kk) ^ (col16 & 7)) * 8;
            bf16x8 af[4];
            #pragma unroll
            for (int mt = 0; mt < 4; mt++)
                af[mt] = *(const bf16x8*)&As[(wm * 64 + mt * 16 + col16) * 64 + sw];
            bf16x8 bfr[3];
            #pragma unroll
            for (int nt = 0; nt < 3; nt++)
                bfr[nt] = *(const bf16x8*)&Bss[(wn * 48 + nt * 16 + col16) * 64 + sw];
            #pragma unroll
            for (int mt = 0; mt < 4; mt++)
                #pragma unroll
                for (int nt = 0; nt < 3; nt++)
                    acc[mt][nt] = __builtin_amdgcn_mfma_f32_16x16x32_bf16(
                        af[mt], bfr[nt], acc[mt][nt], 0, 0, 0);
        }
        asm volatile("s_waitcnt lgkmcnt(0)" ::: "memory");
        __builtin_amdgcn_s_barrier();
    }

    #pragma unroll
    for (int nt = 0; nt < 3; nt++) {
        int n = wn * 48 + nt * 16 + col16;
        float obv = ob[n];
        #pragma unroll
        for (int mt = 0; mt < 4; mt++)
            #pragma unroll
            for (int r = 0; r < 4; r++)
                out[(size_t)(m0 + wm * 64 + mt * 16 + q * 4 + r) * EMB + n] =
                    acc[mt][nt][r] + obv;
    }
}

extern "C" void kernel_launch(void* const* d_in, const int* in_sizes, int n_in,
                              void* d_out, int out_size, void* d_ws, size_t ws_size,
                              hipStream_t stream)
{
    (void)in_sizes; (void)n_in; (void)out_size; (void)ws_size;
    const float* x     = (const float*)d_in[0];
    const float* p_w   = (const float*)d_in[1];
    const float* p_b   = (const float*)d_in[2];
    const float* q_w   = (const float*)d_in[3];
    const float* q_b   = (const float*)d_in[4];
    const float* v_w   = (const float*)d_in[5];
    const float* v_b   = (const float*)d_in[6];
    const float* o_w   = (const float*)d_in[7];
    const float* o_b   = (const float*)d_in[8];
    const float* slope = (const float*)d_in[9];
    const float* t1_w0 = (const float*)d_in[10];
    const float* t1_b0 = (const float*)d_in[11];
    const float* t1_ws = (const float*)d_in[12];
    const float* t1_bs = (const float*)d_in[13];
    const float* t1_wo = (const float*)d_in[14];
    const float* t1_bo = (const float*)d_in[15];
    const float* t2_w0 = (const float*)d_in[16];
    const float* t2_b0 = (const float*)d_in[17];
    const float* t2_ws = (const float*)d_in[18];
    const float* t2_bs = (const float*)d_in[19];
    const float* t2_wo = (const float*)d_in[20];
    const float* t2_bo = (const float*)d_in[21];

    char* ws = (char*)d_ws;
    float* A1  = (float*)ws;                     // 258048 B
    float* A2  = (float*)(ws + 258048);          // 258048 B
    u16*   PT  = (u16*)(ws + 516096);            // 28901376 B (P_T)
    u16*   QVT = (u16*)(ws + 29417472);          // 28901376 B
    u16*   UT  = (u16*)(ws + 58318848);          // 28901376 B
    u16*   xb  = (u16*)(ws + 87220224);          // 9633792 B
    u16*   wb  = (u16*)(ws + 96854016);          // 663552 B
    u16*   owb = (u16*)(ws + 97517568);          // 221184 B
    u16*   T1t = (u16*)(ws + 97738752);          // 4718592 B
    u16*   T2t = (u16*)(ws + 102457344);         // 4718592 B

    convert_kernel<<<(XCH + 4*WCH + 255) / 256, 256, 0, stream>>>(
        x, p_w, q_w, v_w, o_w, xb, wb, owb);
    rpe_kernel<<<224, 576, 0, stream>>>(slope,
        t1_w0, t1_b0, t1_ws, t1_bs, t1_wo, t1_bo,
        t2_w0, t2_b0, t2_ws, t2_bs, t2_wo, t2_bo, A1, A2);
    tbuild_kernel<<<dim3(576, 2), 256, 0, stream>>>(A1, A2, T1t, T2t);
    proj_kernel<<<dim3(TOK / 128, D1 / 64), 512, 0, stream>>>(
        xb, wb, p_b, q_b, v_b, PT, QVT);
    tno_mfma<<<dim3(D1, NB), 256, 0, stream>>>(QVT, T1t, T2t, PT, UT);
    outproj_kernel<<<TOK / 128, 512, 0, stream>>>(
        UT, owb, o_b, (float*)d_out);
}